// Round 1
// baseline (74.820 us; speedup 1.0000x reference)
//
#include <hip/hip_runtime.h>

#define NB 32
#define NF 64
#define NN 128
#define EPSF 1e-9f

// ---------------------------------------------------------------------------
// Pass 1: per-(b,f) masked trace / trace-of-square / node count.
// One block per (b,f) 128x128 matrix. Matrix staged in LDS (exactly 64 KB)
// with XOR swizzle addr = i*128 + (k ^ (i&31)) so both the row-major and the
// transposed read patterns are <=2-way bank conflicts (free on CDNA4).
// trace_sq = sum_{i,k} x[i,k] * x[k,i] * mask[i]^2  (== tr(x@x . diagmask))
// ---------------------------------------------------------------------------
__global__ __launch_bounds__(256) void mfb_stats(
    const float* __restrict__ x, const float* __restrict__ mask,
    float* __restrict__ mean_bf, float* __restrict__ var_bf) {
  __shared__ float tile[NN * NN];  // 65536 bytes, reused for block reduction
  const int tid = threadIdx.x;
  const int bf = blockIdx.x;
  const int b = bf >> 6;  // F = 64
  const float* xp = x + (size_t)bf * (NN * NN);
  const int lane = tid & 63;

  // mask row held in registers across each wave's 64 lanes
  float m0 = mask[b * NN + lane];
  float m1 = mask[b * NN + 64 + lane];
  float msq0 = m0 * m0;
  float msq1 = m1 * m1;

  // stage x[b,f] into LDS (coalesced scalar loads, conflict-free swizzled writes)
  const int kcol = tid & 127;
  const int ib = tid >> 7;  // 0 or 1
#pragma unroll 8
  for (int c = 0; c < 64; ++c) {
    int i = 2 * c + ib;
    tile[i * NN + (kcol ^ (i & 31))] = xp[c * 256 + tid];
  }
  __syncthreads();

  float tr = 0.f, nump = 0.f;
  if (tid < 64) nump = msq0 + msq1;  // count num once (wave 0 only)
  if (tid < 128) {
    // diagonal element x[i,i], i = tid
    float d = tile[tid * NN + (tid ^ (tid & 31))];
    tr = d * ((tid < 64) ? msq0 : msq1);
  }

  // trace of x@x: each thread owns half of row irow (64 columns)
  const int irow = tid >> 1;
  const int k0 = (tid & 1) << 6;
  float mq = (irow < 64) ? __shfl(msq0, irow, 64) : __shfl(msq1, irow - 64, 64);
  const int cxor = irow & 31;
  const int rowbase = irow * NN;
  float acc = 0.f;
#pragma unroll
  for (int c = 0; c < 64; ++c) {
    int k = k0 + c;
    float a = tile[rowbase + (k ^ cxor)];          // x[irow, k]
    float bt = tile[k * NN + (irow ^ (k & 31))];   // x[k, irow]
    acc = fmaf(a, bt, acc);
  }
  float trsq = acc * mq;

  // block reduction: wave shfl, then LDS (reusing tile) across 4 waves
#pragma unroll
  for (int off = 32; off > 0; off >>= 1) {
    tr   += __shfl_down(tr, off, 64);
    trsq += __shfl_down(trsq, off, 64);
    nump += __shfl_down(nump, off, 64);
  }
  __syncthreads();  // all tile reads complete before reuse
  if (lane == 0) {
    int w = tid >> 6;
    tile[w * 3 + 0] = tr;
    tile[w * 3 + 1] = trsq;
    tile[w * 3 + 2] = nump;
  }
  __syncthreads();
  if (tid == 0) {
    float trs = tile[0] + tile[3] + tile[6] + tile[9];
    float tq  = tile[1] + tile[4] + tile[7] + tile[10];
    float num = tile[2] + tile[5] + tile[8] + tile[11];
    float num2 = fmaxf(num - 1.f, 1.f);
    mean_bf[bf] = trs / num;
    var_bf[bf]  = tq / num2 - trs * trs / (num * num2);
  }
}

// ---------------------------------------------------------------------------
// Pass 2: reduce over batch, momentum update, fold gain / sqrt(var) per f.
// ---------------------------------------------------------------------------
__global__ void mfb_finalize(
    const float* __restrict__ mean_bf, const float* __restrict__ var_bf,
    const float* __restrict__ w, const float* __restrict__ wexp,
    const float* __restrict__ wbias, const float* __restrict__ rmean,
    const float* __restrict__ rvar, const int* __restrict__ steps,
    float* __restrict__ rmA, float* __restrict__ sA) {
  int f = threadIdx.x;  // 64 threads
  float ms = 0.f, vs = 0.f;
  for (int b = 0; b < NB; ++b) {
    ms += mean_bf[b * NF + f];
    vs += var_bf[b * NF + f];
  }
  ms *= (1.f / NB);
  vs *= (1.f / NB);
  int st = steps[0];
  float mom = 0.997f;
  if (st < 100) {
    float beta = (float)st * 0.01f;
    mom = 0.997f * beta + 0.8f * (1.f - beta);
  }
  float rm = mom * rmean[f] + (1.f - mom) * ms;
  float rv = mom * rvar[f] + (1.f - mom) * vs;
  float gain = w[f] * expf(wexp[f]) + wbias[f];
  rmA[f] = rm;
  sA[f] = gain / (sqrtf(rv) + EPSF);
}

// ---------------------------------------------------------------------------
// Pass 3: elementwise apply, float4 vectorized.
// out = (x - rm[f]*delta(i,j)) * m[b,i]*m[b,j] * s[f] + bias[f]*delta(i,j)
// ---------------------------------------------------------------------------
__global__ __launch_bounds__(256) void mfb_apply(
    const float4* __restrict__ x4, const float* __restrict__ mask,
    const float* __restrict__ rmA, const float* __restrict__ sA,
    const float* __restrict__ bias, float4* __restrict__ out4) {
  const int total = NB * NF * NN * NN / 4;  // 8388608
  for (int v = blockIdx.x * 256 + threadIdx.x; v < total;
       v += gridDim.x * 256) {
    float4 xv = x4[v];
    int j0 = (v & 31) << 2;
    int i = (v >> 5) & 127;
    int f = (v >> 12) & 63;
    int b = v >> 18;
    float4 mj = ((const float4*)(mask + b * NN))[v & 31];
    float mi = mask[b * NN + i];
    float s = sA[f];
    float rm = rmA[f];
    float bi = bias[f];
    float cs = mi * s;
    float4 o;
    o.x = (xv.x - ((i == j0    ) ? rm : 0.f)) * (cs * mj.x) + ((i == j0    ) ? bi : 0.f);
    o.y = (xv.y - ((i == j0 + 1) ? rm : 0.f)) * (cs * mj.y) + ((i == j0 + 1) ? bi : 0.f);
    o.z = (xv.z - ((i == j0 + 2) ? rm : 0.f)) * (cs * mj.z) + ((i == j0 + 2) ? bi : 0.f);
    o.w = (xv.w - ((i == j0 + 3) ? rm : 0.f)) * (cs * mj.w) + ((i == j0 + 3) ? bi : 0.f);
    out4[v] = o;
  }
}

extern "C" void kernel_launch(void* const* d_in, const int* in_sizes, int n_in,
                              void* d_out, int out_size, void* d_ws, size_t ws_size,
                              hipStream_t stream) {
  const float* x     = (const float*)d_in[0];
  const float* mask  = (const float*)d_in[1];
  const float* w     = (const float*)d_in[2];
  const float* wexp  = (const float*)d_in[3];
  const float* wbias = (const float*)d_in[4];
  const float* bias  = (const float*)d_in[5];
  const float* rmean = (const float*)d_in[6];
  const float* rvar  = (const float*)d_in[7];
  const int*   steps = (const int*)d_in[8];

  float* ws = (float*)d_ws;
  float* mean_bf = ws;                       // [B*F]
  float* var_bf  = ws + NB * NF;             // [B*F]
  float* rmA     = ws + 2 * NB * NF;         // [F]
  float* sA      = rmA + NF;                 // [F]

  mfb_stats<<<NB * NF, 256, 0, stream>>>(x, mask, mean_bf, var_bf);
  mfb_finalize<<<1, NF, 0, stream>>>(mean_bf, var_bf, w, wexp, wbias,
                                     rmean, rvar, steps, rmA, sA);
  mfb_apply<<<2048, 256, 0, stream>>>((const float4*)x, mask, rmA, sA, bias,
                                      (float4*)d_out);
}

// Round 3
// 72.598 us; speedup vs baseline: 1.0306x; 1.0306x over previous
//
#include <hip/hip_runtime.h>

#define NB 32
#define NF 64
#define NN 128
#define EPSF 1e-9f

typedef float f32x4 __attribute__((ext_vector_type(4)));

// ---------------------------------------------------------------------------
// Pass 1: per-(b,f) masked trace / trace-of-square / node count.
// One block per (b,f) 128x128 matrix. Matrix staged in LDS (exactly 64 KB)
// with XOR swizzle addr = i*128 + (k ^ (i&31)) so both the row-major and the
// transposed read patterns are <=2-way bank conflicts (free on CDNA4).
// trace_sq = sum_{i,k} x[i,k] * x[k,i] * mask[i]^2  (== tr(x@x . diagmask))
// ---------------------------------------------------------------------------
__global__ __launch_bounds__(256) void mfb_stats(
    const float* __restrict__ x, const float* __restrict__ mask,
    float* __restrict__ mean_bf, float* __restrict__ var_bf) {
  __shared__ float tile[NN * NN];  // 65536 bytes, reused for block reduction
  const int tid = threadIdx.x;
  const int bf = blockIdx.x;
  const int b = bf >> 6;  // F = 64
  const float* xp = x + (size_t)bf * (NN * NN);
  const int lane = tid & 63;

  // mask row held in registers across each wave's 64 lanes
  float m0 = mask[b * NN + lane];
  float m1 = mask[b * NN + 64 + lane];
  float msq0 = m0 * m0;
  float msq1 = m1 * m1;

  // stage x[b,f] into LDS (coalesced scalar loads, conflict-free swizzled writes)
  const int kcol = tid & 127;
  const int ib = tid >> 7;  // 0 or 1
#pragma unroll 8
  for (int c = 0; c < 64; ++c) {
    int i = 2 * c + ib;
    tile[i * NN + (kcol ^ (i & 31))] = xp[c * 256 + tid];
  }
  __syncthreads();

  float tr = 0.f, nump = 0.f;
  if (tid < 64) nump = msq0 + msq1;  // count num once (wave 0 only)
  if (tid < 128) {
    // diagonal element x[i,i], i = tid
    float d = tile[tid * NN + (tid ^ (tid & 31))];
    tr = d * ((tid < 64) ? msq0 : msq1);
  }

  // trace of x@x: each thread owns half of row irow (64 columns)
  const int irow = tid >> 1;
  const int k0 = (tid & 1) << 6;
  float mq = (irow < 64) ? __shfl(msq0, irow, 64) : __shfl(msq1, irow - 64, 64);
  const int cxor = irow & 31;
  const int rowbase = irow * NN;
  float acc = 0.f;
#pragma unroll
  for (int c = 0; c < 64; ++c) {
    int k = k0 + c;
    float a = tile[rowbase + (k ^ cxor)];          // x[irow, k]
    float bt = tile[k * NN + (irow ^ (k & 31))];   // x[k, irow]
    acc = fmaf(a, bt, acc);
  }
  float trsq = acc * mq;

  // block reduction: wave shfl, then LDS (reusing tile) across 4 waves
#pragma unroll
  for (int off = 32; off > 0; off >>= 1) {
    tr   += __shfl_down(tr, off, 64);
    trsq += __shfl_down(trsq, off, 64);
    nump += __shfl_down(nump, off, 64);
  }
  __syncthreads();  // all tile reads complete before reuse
  if (lane == 0) {
    int w = tid >> 6;
    tile[w * 3 + 0] = tr;
    tile[w * 3 + 1] = trsq;
    tile[w * 3 + 2] = nump;
  }
  __syncthreads();
  if (tid == 0) {
    float trs = tile[0] + tile[3] + tile[6] + tile[9];
    float tq  = tile[1] + tile[4] + tile[7] + tile[10];
    float num = tile[2] + tile[5] + tile[8] + tile[11];
    float num2 = fmaxf(num - 1.f, 1.f);
    mean_bf[bf] = trs / num;
    var_bf[bf]  = tq / num2 - trs * trs / (num * num2);
  }
}

// ---------------------------------------------------------------------------
// Pass 2 (fused finalize + apply): one block per (b,f) matrix.
// Block first reduces the 32 batch partials for its f, computes the
// momentum-updated running stats and the folded scale, then streams the
// 64 KB matrix: out = (x - rm*delta) * mi*mj*s + bias*delta.
// Output written with NON-TEMPORAL stores so out does not evict x from the
// 256 MB Infinity Cache -> the x re-read stays L3-resident.
// ---------------------------------------------------------------------------
__global__ __launch_bounds__(256) void mfb_apply(
    const f32x4* __restrict__ x4, const float* __restrict__ mask,
    const float* __restrict__ mean_bf, const float* __restrict__ var_bf,
    const float* __restrict__ w, const float* __restrict__ wexp,
    const float* __restrict__ wbias, const float* __restrict__ bias,
    const float* __restrict__ rmean, const float* __restrict__ rvar,
    const int* __restrict__ steps, f32x4* __restrict__ out4) {
  const int bf = blockIdx.x;
  const int b = bf >> 6;
  const int f = bf & 63;
  const int tid = threadIdx.x;
  __shared__ float smask[NN];
  __shared__ float sc[3];  // rm, s, bias[f]

  if (tid < NN) smask[tid] = mask[b * NN + tid];
  if (tid < 32) {
    float ms = mean_bf[tid * NF + f];
    float vs = var_bf[tid * NF + f];
#pragma unroll
    for (int off = 16; off > 0; off >>= 1) {
      ms += __shfl_down(ms, off, 32);
      vs += __shfl_down(vs, off, 32);
    }
    if (tid == 0) {
      ms *= (1.f / NB);
      vs *= (1.f / NB);
      int st = steps[0];
      float mom = 0.997f;
      if (st < 100) {
        float beta = (float)st * 0.01f;
        mom = 0.997f * beta + 0.8f * (1.f - beta);
      }
      float rm = mom * rmean[f] + (1.f - mom) * ms;
      float rv = mom * rvar[f] + (1.f - mom) * vs;
      float gain = w[f] * expf(wexp[f]) + wbias[f];
      sc[0] = rm;
      sc[1] = gain / (sqrtf(rv) + EPSF);
      sc[2] = bias[f];
    }
  }
  __syncthreads();

  const float rm = sc[0];
  const float s = sc[1];
  const float bi = sc[2];
  const f32x4 mj4 = ((const f32x4*)smask)[tid & 31];
  const int j0 = (tid & 31) << 2;
  const int wv = tid >> 5;
  const f32x4* xp = x4 + (size_t)bf * 4096;
  f32x4* op = out4 + (size_t)bf * 4096;

#pragma unroll
  for (int c = 0; c < 16; ++c) {
    const int idx = c * 256 + tid;
    const int i = c * 8 + wv;
    f32x4 xv = xp[idx];
    float cs = smask[i] * s;
    f32x4 o;
    o.x = (xv.x - ((i == j0    ) ? rm : 0.f)) * (cs * mj4.x) + ((i == j0    ) ? bi : 0.f);
    o.y = (xv.y - ((i == j0 + 1) ? rm : 0.f)) * (cs * mj4.y) + ((i == j0 + 1) ? bi : 0.f);
    o.z = (xv.z - ((i == j0 + 2) ? rm : 0.f)) * (cs * mj4.z) + ((i == j0 + 2) ? bi : 0.f);
    o.w = (xv.w - ((i == j0 + 3) ? rm : 0.f)) * (cs * mj4.w) + ((i == j0 + 3) ? bi : 0.f);
    __builtin_nontemporal_store(o, &op[idx]);
  }
}

extern "C" void kernel_launch(void* const* d_in, const int* in_sizes, int n_in,
                              void* d_out, int out_size, void* d_ws, size_t ws_size,
                              hipStream_t stream) {
  const float* x     = (const float*)d_in[0];
  const float* mask  = (const float*)d_in[1];
  const float* w     = (const float*)d_in[2];
  const float* wexp  = (const float*)d_in[3];
  const float* wbias = (const float*)d_in[4];
  const float* bias  = (const float*)d_in[5];
  const float* rmean = (const float*)d_in[6];
  const float* rvar  = (const float*)d_in[7];
  const int*   steps = (const int*)d_in[8];

  float* ws = (float*)d_ws;
  float* mean_bf = ws;                       // [B*F]
  float* var_bf  = ws + NB * NF;             // [B*F]

  mfb_stats<<<NB * NF, 256, 0, stream>>>(x, mask, mean_bf, var_bf);
  mfb_apply<<<NB * NF, 256, 0, stream>>>((const f32x4*)x, mask, mean_bf, var_bf,
                                         w, wexp, wbias, bias, rmean, rvar,
                                         steps, (f32x4*)d_out);
}